// Round 4
// baseline (6406.338 us; speedup 1.0000x reference)
//
#include <hip/hip_runtime.h>
#include <hip/hip_fp16.h>

// Decoder: 2-layer LSTM (H=256), T=512, B=256, scalar output feedback.
// Round 7: NB=2 re-applied (round-0 structure) on the round-6 fdot2 skeleton.
//  - Round-6 post-mortem: kernel is L2-BW-bound (1.41 MB/CU/step streamed =
//    ~87% of per-XCD L2 port); VALU only 33%. fdot2 made dots cheap, so
//    amortize each weight fetch over 2 batch elements: grid=128, NB=2.
//    Chip L2 demand halves; VALU grows by only the (cheap) dot path.
//  - Keeps: uint4 weight loads (spill-proof), bit_cast->fdot2, LICM fence,
//    128KB LDS cache of whh0 windows 0..7, redundant per-wave pred reduce.

namespace {

constexpr int kB = 256, kT = 512, kH = 256;
constexpr int kWin = 32;                       // 256 k-values / 8 per window
constexpr int kTiles = kWin * 1024;            // uint4 tiles per matrix
constexpr size_t kWsNeeded = 3 * (size_t)kTiles * 16;  // 1.5 MB
constexpr int kLdsWin = 8;                     // whh0 windows cached in LDS (128 KB)

typedef _Float16 h2_t __attribute__((ext_vector_type(2)));
struct alignas(16) H8 { __half2 h[4]; };       // pack-side view of 8 fp16

__device__ __forceinline__ float fsig(float v) { return 1.0f / (1.0f + __expf(-v)); }

// 8-wide fp16 dot-accumulate from two raw uint4 registers.
__device__ __forceinline__ float dot8(uint4 w, uint4 x, float a) {
#if __has_builtin(__builtin_amdgcn_fdot2)
  a = __builtin_amdgcn_fdot2(__builtin_bit_cast(h2_t, w.x),
                             __builtin_bit_cast(h2_t, x.x), a, false);
  a = __builtin_amdgcn_fdot2(__builtin_bit_cast(h2_t, w.y),
                             __builtin_bit_cast(h2_t, x.y), a, false);
  a = __builtin_amdgcn_fdot2(__builtin_bit_cast(h2_t, w.z),
                             __builtin_bit_cast(h2_t, x.z), a, false);
  a = __builtin_amdgcn_fdot2(__builtin_bit_cast(h2_t, w.w),
                             __builtin_bit_cast(h2_t, x.w), a, false);
#else
  {
    float2 f0 = __half22float2(__builtin_bit_cast(__half2, w.x));
    float2 x0 = __half22float2(__builtin_bit_cast(__half2, x.x));
    float2 f1 = __half22float2(__builtin_bit_cast(__half2, w.y));
    float2 x1 = __half22float2(__builtin_bit_cast(__half2, x.y));
    float2 f2 = __half22float2(__builtin_bit_cast(__half2, w.z));
    float2 x2 = __half22float2(__builtin_bit_cast(__half2, x.z));
    float2 f3 = __half22float2(__builtin_bit_cast(__half2, w.w));
    float2 x3 = __half22float2(__builtin_bit_cast(__half2, x.w));
    a = fmaf(f0.x, x0.x, a); a = fmaf(f0.y, x0.y, a);
    a = fmaf(f1.x, x1.x, a); a = fmaf(f1.y, x1.y, a);
    a = fmaf(f2.x, x2.x, a); a = fmaf(f2.y, x2.y, a);
    a = fmaf(f3.x, x3.x, a); a = fmaf(f3.y, x3.y, a);
  }
#endif
  return a;
}

// dst[win*1024 + j] holds w[j][8win..8win+7]; lane-consecutive j => coalesced.
__global__ __launch_bounds__(256) void pack_w(const float* __restrict__ s0,
                                              const float* __restrict__ s1,
                                              const float* __restrict__ s2,
                                              H8* __restrict__ dst) {
  int idx = blockIdx.x * 256 + threadIdx.x;       // 0 .. 3*32768-1
  int mat = idx >> 15;                            // 0..2
  int loc = idx & 32767;                          // win*1024 + j
  int j = loc & 1023, win = loc >> 10;
  const float* src = (mat == 0 ? s0 : (mat == 1 ? s1 : s2)) + j * 256 + win * 8;
  H8 o;
#pragma unroll
  for (int i = 0; i < 4; ++i) o.h[i] = __floats2half2_rn(src[2 * i], src[2 * i + 1]);
  dst[idx] = o;
}

__global__ __launch_bounds__(1024) void decoder_nb2(
    const float* __restrict__ seq, const float* __restrict__ z,
    const float* __restrict__ wih0, const float* __restrict__ bih0,
    const float* __restrict__ bhh0, const float* __restrict__ bih1,
    const float* __restrict__ bhh1, const float* __restrict__ wout,
    const float* __restrict__ bout, const uint4* __restrict__ w0,
    const uint4* __restrict__ w1i, const uint4* __restrict__ w1h,
    float* __restrict__ loss_out) {
  extern __shared__ uint4 lw[];                   // kLdsWin windows of whh0
  __shared__ alignas(16) _Float16 h0h[2][kH];     // hidden, layer 0 (fp16)
  __shared__ alignas(16) _Float16 h1h[2][kH];     // hidden, layer 1 (fp16)
  __shared__ float g4[2][1024];
  __shared__ float spred[2][kH];

  const int tid = threadIdx.x;                    // gate row j
  const int b0 = blockIdx.x * 2;                  // batch pair
  const int m = tid >> 8, hr = tid & 255;         // cell role (tid<512)

  // Stage whh0 windows 0..kLdsWin-1 into LDS (coalesced 16B copies).
#pragma unroll
  for (int i = 0; i < kLdsWin; ++i) lw[i * 1024 + tid] = w0[i * 1024 + tid];

  float c0 = 0.f, c1 = 0.f, woutr = 0.f;
  if (tid < 512) {
    float zv = z[(size_t)(b0 + m) * kH + hr];
    h0h[m][hr] = (_Float16)zv;
    h1h[m][hr] = (_Float16)zv;
    c0 = zv;
    c1 = zv;
    woutr = wout[hr];
  }
  const float wih0_j = wih0[tid];
  const float bias0 = bih0[tid] + bhh0[tid];
  const float bias1 = bih1[tid] + bhh1[tid];
  const float bo = bout[0];
  const bool isG = (tid >= 512) && (tid < 768);   // wave-uniform (waves 8..11)
  float xsA = 0.f, xsB = 0.f, lacc = 0.f;

  const uint4* wp0 = w0 + tid;
  const uint4* wpA = w1i + tid;
  const uint4* wpB = w1h + tid;
  const uint4* lwp = lw + tid;
  const uint4* h0A = (const uint4*)h0h[0];        // 32 windows of 8 halves
  const uint4* h0B = (const uint4*)h0h[1];
  const uint4* h1A = (const uint4*)h1h[0];
  const uint4* h1B = (const uint4*)h1h[1];
  __syncthreads();

  for (int t = 0; t < kT; ++t) {
    // LICM fence (round-5 post-mortem: hoist->spill->scratch-HBM-bound).
    asm volatile("" ::: "memory");

    // ---- layer 0 gates, both batches: one weight fetch, two fdot2 chains --
    float aA = fmaf(xsA, wih0_j, bias0);
    float aB = fmaf(xsB, wih0_j, bias0);
#pragma unroll
    for (int win = 0; win < kLdsWin; ++win) {     // LDS-cached windows
      uint4 w = lwp[win << 10];
      aA = dot8(w, h0A[win], aA);
      aB = dot8(w, h0B[win], aB);
    }
#pragma unroll 4
    for (int win = kLdsWin; win < kWin; ++win) {  // L2-streamed windows
      uint4 w = wp0[(size_t)win << 10];
      aA = dot8(w, h0A[win], aA);
      aB = dot8(w, h0B[win], aB);
    }
    if (isG) { g4[0][tid] = tanhf(aA); g4[1][tid] = tanhf(aB); }
    else     { g4[0][tid] = fsig(aA);  g4[1][tid] = fsig(aB); }
    __syncthreads();
    if (tid < 512) {
      float gi = g4[m][hr];
      float gf = g4[m][hr + 256];
      float gg = g4[m][hr + 512];
      float go = g4[m][hr + 768];
      c0 = fmaf(gf, c0, gi * gg);
      h0h[m][hr] = (_Float16)(go * tanhf(c0));
    }
    __syncthreads();

    // ---- layer 1 gates: Wih1 @ h0new + Whh1 @ h1old, both batches --------
    float bA = bias1;
    float bB = bias1;
#pragma unroll 2
    for (int win = 0; win < kWin; ++win) {
      uint4 wA = wpA[(size_t)win << 10];
      uint4 wB = wpB[(size_t)win << 10];
      bA = dot8(wA, h0A[win], bA);
      bB = dot8(wA, h0B[win], bB);
      bA = dot8(wB, h1A[win], bA);
      bB = dot8(wB, h1B[win], bB);
    }
    if (isG) { g4[0][tid] = tanhf(bA); g4[1][tid] = tanhf(bB); }
    else     { g4[0][tid] = fsig(bA);  g4[1][tid] = fsig(bB); }
    __syncthreads();
    if (tid < 512) {
      float gi = g4[m][hr];
      float gf = g4[m][hr + 256];
      float gg = g4[m][hr + 512];
      float go = g4[m][hr + 768];
      c1 = fmaf(gf, c1, gi * gg);
      float hn = go * tanhf(c1);                  // fp32, pre-rounding
      h1h[m][hr] = (_Float16)hn;
      spred[m][hr] = hn * woutr;                  // pred path stays fp32
    }
    __syncthreads();

    // ---- redundant per-wave reduce: preds stay in-register in every wave --
    {
      int ln = tid & 63;
      float vA = spred[0][ln] + spred[0][ln + 64] + spred[0][ln + 128] +
                 spred[0][ln + 192];
      float vB = spred[1][ln] + spred[1][ln + 64] + spred[1][ln + 128] +
                 spred[1][ln + 192];
#pragma unroll
      for (int off = 32; off > 0; off >>= 1) {
        vA += __shfl_down(vA, off);
        vB += __shfl_down(vB, off);
      }
      float predA = __shfl(vA, 0) + bo;           // broadcast within wave
      float predB = __shfl(vB, 0) + bo;
      xsA = predA;                                // feedback for next step
      xsB = predB;
      if (tid == 0) {
        float dA = seq[(size_t)b0 * kT + t] - predA;
        float dB = seq[(size_t)(b0 + 1) * kT + t] - predB;
        lacc = fmaf(dA, dA, lacc);
        lacc = fmaf(dB, dB, lacc);
      }
    }
    // no barrier needed: next writer of spred passes 3 barriers first
  }

  if (tid == 0) atomicAdd(loss_out, lacc * (1.0f / ((float)kB * (float)kT)));
}

// ---------------- fallback (reads d_in directly, fp32) ---------------------
__global__ __launch_bounds__(1024) void decoder_fallback(
    const float* __restrict__ seq, const float* __restrict__ z,
    const float* __restrict__ wih0, const float* __restrict__ bih0,
    const float* __restrict__ bhh0, const float* __restrict__ whh0,
    const float* __restrict__ wih1, const float* __restrict__ whh1,
    const float* __restrict__ bih1, const float* __restrict__ bhh1,
    const float* __restrict__ wout, const float* __restrict__ bout,
    float* __restrict__ loss_out) {
  __shared__ float h0s[kH], h1s[kH], g4[1024];
  __shared__ float xs_s;
  const int tid = threadIdx.x;
  const int b = blockIdx.x;
  float c0r = 0.f, c1r = 0.f;
  if (tid < kH) {
    float zv = z[b * kH + tid];
    h0s[tid] = zv; h1s[tid] = zv; c0r = zv; c1r = zv;
  }
  if (tid == 0) xs_s = 0.f;
  const float wih0_j = wih0[tid];
  const float bias0_j = bih0[tid] + bhh0[tid];
  const float bias1_j = bih1[tid] + bhh1[tid];
  const float wout_r = (tid < kH) ? wout[tid] : 0.f;
  const float bo = bout[0];
  float lacc = 0.f;
  __syncthreads();
  for (int t = 0; t < kT; ++t) {
    float a0 = fmaf(xs_s, wih0_j, bias0_j);
    for (int k = 0; k < kH; ++k) a0 = fmaf(whh0[tid * kH + k], h0s[k], a0);
    g4[tid] = a0;
    __syncthreads();
    if (tid < kH) {
      float ig = fsig(g4[tid]), fg = fsig(g4[tid + 256]);
      float gg = tanhf(g4[tid + 512]), og = fsig(g4[tid + 768]);
      c0r = fmaf(fg, c0r, ig * gg);
      h0s[tid] = og * tanhf(c0r);
    }
    __syncthreads();
    float a1 = bias1_j;
    for (int k = 0; k < kH; ++k) a1 = fmaf(wih1[tid * kH + k], h0s[k], a1);
    for (int k = 0; k < kH; ++k) a1 = fmaf(whh1[tid * kH + k], h1s[k], a1);
    g4[tid] = a1;
    __syncthreads();
    if (tid < kH) {
      float ig = fsig(g4[tid]), fg = fsig(g4[tid + 256]);
      float gg = tanhf(g4[tid + 512]), og = fsig(g4[tid + 768]);
      c1r = fmaf(fg, c1r, ig * gg);
      float h1 = og * tanhf(c1r);
      h1s[tid] = h1;
      g4[tid] = h1 * wout_r;
    }
    __syncthreads();
    if (tid < 64) {
      float v = g4[tid] + g4[tid + 64] + g4[tid + 128] + g4[tid + 192];
#pragma unroll
      for (int off = 32; off > 0; off >>= 1) v += __shfl_down(v, off);
      if (tid == 0) {
        float pred = v + bo;
        float d = seq[b * kT + t] - pred;
        lacc = fmaf(d, d, lacc);
        xs_s = pred;
      }
    }
    __syncthreads();
  }
  if (tid == 0) atomicAdd(loss_out, lacc * (1.0f / (float)(kB * kT)));
}

}  // namespace

extern "C" void kernel_launch(void* const* d_in, const int* in_sizes, int n_in,
                              void* d_out, int out_size, void* d_ws, size_t ws_size,
                              hipStream_t stream) {
  const float* seq = (const float*)d_in[0];
  const float* z = (const float*)d_in[1];
  const float* wih0 = (const float*)d_in[3];
  const float* whh0 = (const float*)d_in[4];
  const float* bih0 = (const float*)d_in[5];
  const float* bhh0 = (const float*)d_in[6];
  const float* wih1 = (const float*)d_in[7];
  const float* whh1 = (const float*)d_in[8];
  const float* bih1 = (const float*)d_in[9];
  const float* bhh1 = (const float*)d_in[10];
  const float* wout = (const float*)d_in[11];
  const float* bout = (const float*)d_in[12];
  float* out = (float*)d_out;

  hipMemsetAsync(out, 0, sizeof(float), stream);

  if (ws_size >= kWsNeeded) {
    H8* wpk = (H8*)d_ws;  // [3][32768] tiles: whh0, wih1, whh1
    pack_w<<<384, 256, 0, stream>>>(whh0, wih1, whh1, wpk);
    // 128KB dynamic LDS cache forces 1 block/CU; 128 blocks spread over
    // 128 distinct CUs, each serving a batch pair from one weight stream.
    const uint4* wu = (const uint4*)wpk;
    decoder_nb2<<<kB / 2, 1024, kLdsWin * 1024 * (int)sizeof(uint4), stream>>>(
        seq, z, wih0, bih0, bhh0, bih1, bhh1, wout, bout, wu,
        wu + kTiles, wu + 2 * kTiles, out);
  } else {
    decoder_fallback<<<kB, 1024, 0, stream>>>(seq, z, wih0, bih0, bhh0, whh0,
                                              wih1, whh1, bih1, bhh1, wout, bout,
                                              out);
  }
}